// Round 1
// baseline (372.534 us; speedup 1.0000x reference)
//
#include <hip/hip_runtime.h>

// rnn_lyapunov: B=64,T=2048,NIN=64,NH=512,NOUT=64
// Time-parallel chunked RNN: contraction ||A||~0.36 => W=16 warmup steps
// reconverge each chunk's state; chunk0's clamped-t warmup == the fixed-point
// iteration for h0. All GEMMs via mfma_f32_16x16x32_bf16.

#define T_LEN 2048
#define B_SZ  64
#define H_DIM 512
#define N_IN  64
#define N_OUT 64
#define L_CH  8                  // output steps per chunk
#define W_UP  16                 // warmup steps per chunk
#define S_TOT (W_UP + L_CH)      // 24 steps total per chunk
#define N_CH  (T_LEN / L_CH)     // 256 chunks = 256 workgroups (1 per CU)

typedef __attribute__((ext_vector_type(8))) short short8;   // 8 bf16 in 4 VGPRs
typedef __attribute__((ext_vector_type(4))) float f32x4;

__device__ __forceinline__ unsigned short f2bf(float f) {
  union { float f; unsigned u; } v; v.f = f;
  return (unsigned short)((v.u + 0x7FFFu + ((v.u >> 16) & 1u)) >> 16);  // RNE
}

__device__ __forceinline__ float tanh_fast(float x) {
  float e = __expf(2.f * x);          // v_exp_f32 path; saturates correctly
  return 1.f - 2.f / (e + 1.f);
}

// ---- pack weights into MFMA B-operand fragment layout ----------------------
// B-frag for 16x16x32: lane L holds B[k = 32*kk + 8*(L>>4) + j][n = 16*nt + (L&15)]
// A_pk  [kk=16][nt=32][lane=64][8] : B[k][n] = W_hh[n][k]*omega[k]^2
// Wih_pk[kk= 2][nt=32][lane=64][8] : B[k][n] = W_ih[n][k]      (k<64, n<512)
// Wlin_pk[kk=16][nt=4][lane=64][8] : B[k][n] = W_lin[n][k]     (k<512, n<64)
__global__ __launch_bounds__(256) void pack_kernel(
    const float* __restrict__ W_ih, const float* __restrict__ W_hh,
    const float* __restrict__ omega, const float* __restrict__ W_lin,
    unsigned short* __restrict__ Apk, unsigned short* __restrict__ WihPk,
    unsigned short* __restrict__ WlinPk)
{
  int id = blockIdx.x * 256 + threadIdx.x;
  if (id < 32768) {                       // A pack: (kk*32+nt)*64+lane
    int kk = id >> 11, rem = id & 2047, nt = rem >> 6, lane = rem & 63;
    int q = lane >> 4, c = lane & 15;
    int n = nt * 16 + c, kb = kk * 32 + q * 8;
    unsigned short* dst = Apk + (size_t)id * 8;
    #pragma unroll
    for (int j = 0; j < 8; j++) {
      int k = kb + j; float w = omega[k];
      dst[j] = f2bf(W_hh[(size_t)n * H_DIM + k] * w * w);
    }
  } else if (id < 36864) {                // W_ih pack
    int id2 = id - 32768;
    int kk = id2 >> 11, rem = id2 & 2047, nt = rem >> 6, lane = rem & 63;
    int q = lane >> 4, c = lane & 15;
    int n = nt * 16 + c, kb = kk * 32 + q * 8;
    unsigned short* dst = WihPk + (size_t)id2 * 8;
    #pragma unroll
    for (int j = 0; j < 8; j++) dst[j] = f2bf(W_ih[(size_t)n * N_IN + kb + j]);
  } else if (id < 40960) {                // W_lin pack
    int id3 = id - 36864;
    int kk = id3 >> 8, rem = id3 & 255, nt = rem >> 6, lane = rem & 63;
    int q = lane >> 4, c = lane & 15;
    int n = nt * 16 + c, kb = kk * 32 + q * 8;
    unsigned short* dst = WlinPk + (size_t)id3 * 8;
    #pragma unroll
    for (int j = 0; j < 8; j++) dst[j] = f2bf(W_lin[(size_t)n * H_DIM + kb + j]);
  }
}

// ---- main time-parallel recurrence kernel ----------------------------------
// grid = 256 blocks (1 chunk each, 1 block/CU via 152KB LDS), 512 threads = 8 waves.
// Wave w owns output cols [64w, 64w+64) of h (nt = 4w..4w+3).
__global__ __launch_bounds__(512) void rnn_kernel(
    const float* __restrict__ u, const float* __restrict__ b_ih,
    const float* __restrict__ b_hh, const float* __restrict__ b_lin,
    const unsigned short* __restrict__ Apk,
    const unsigned short* __restrict__ WihPk,
    const unsigned short* __restrict__ WlinPk,
    float* __restrict__ out)
{
  __shared__ unsigned short h_buf[2][B_SZ][H_DIM + 8];   // +8 pad: 2-way-bank only
  __shared__ unsigned short u_buf[2][B_SZ][N_IN + 8];
  __shared__ float bsum[H_DIM];
  __shared__ float blin_s[N_OUT];

  const int tid = threadIdx.x;
  const int w = tid >> 6;
  const int lane = tid & 63;
  const int q = lane >> 4, c = lane & 15;
  const int chunk = blockIdx.x;
  const int t0 = chunk * L_CH;

  for (int i = tid; i < H_DIM; i += 512) bsum[i] = b_ih[i] + b_hh[i];
  if (tid < N_OUT) blin_s[tid] = b_lin[tid];
  for (int i = tid; i < B_SZ * (H_DIM + 8); i += 512)
    ((unsigned short*)h_buf[0])[i] = 0;                   // h starts at zero
  {    // stage u for step 0: t_in(0) = max(t0 - W, 0)
    int t = t0 - W_UP; if (t < 0) t = 0;
    int row = tid >> 3, cb = (tid & 7) * 8;
    const float* src = u + ((size_t)row * T_LEN + t) * N_IN + cb;
    #pragma unroll
    for (int j = 0; j < 8; j++) u_buf[0][row][cb + j] = f2bf(src[j]);
  }
  __syncthreads();

  f32x4 acc[4][4];

  for (int s = 0; s < S_TOT; s++) {
    const int cur = s & 1, nxt = cur ^ 1;

    // prefetch u for next step into registers
    float upf[8];
    {
      int tn = t0 - W_UP + s + 1;
      if (tn < 0) tn = 0; if (tn > T_LEN - 1) tn = T_LEN - 1;
      int row = tid >> 3, cb = (tid & 7) * 8;
      const float* src = u + ((size_t)row * T_LEN + tn) * N_IN + cb;
      #pragma unroll
      for (int j = 0; j < 8; j++) upf[j] = src[j];
    }

    #pragma unroll
    for (int mt = 0; mt < 4; mt++)
      #pragma unroll
      for (int ntl = 0; ntl < 4; ntl++)
        acc[mt][ntl] = (f32x4){0.f, 0.f, 0.f, 0.f};

    // ---- h @ A^T : K = 512 (A-frags from LDS, B-frags streamed from L2) ----
    #pragma unroll 4
    for (int kk = 0; kk < 16; kk++) {
      short8 afr[4];
      #pragma unroll
      for (int mt = 0; mt < 4; mt++)
        afr[mt] = *(const short8*)&h_buf[cur][mt * 16 + c][kk * 32 + q * 8];
      #pragma unroll
      for (int ntl = 0; ntl < 4; ntl++) {
        const short8 bfr = *(const short8*)(Apk +
            (((size_t)kk * 32 + (4 * w + ntl)) * 64 + lane) * 8);
        #pragma unroll
        for (int mt = 0; mt < 4; mt++)
          acc[mt][ntl] = __builtin_amdgcn_mfma_f32_16x16x32_bf16(
              afr[mt], bfr, acc[mt][ntl], 0, 0, 0);
      }
    }
    // ---- + u_t @ W_ih^T : K = 64, same accumulators ----
    #pragma unroll
    for (int kk = 0; kk < 2; kk++) {
      short8 afr[4];
      #pragma unroll
      for (int mt = 0; mt < 4; mt++)
        afr[mt] = *(const short8*)&u_buf[cur][mt * 16 + c][kk * 32 + q * 8];
      #pragma unroll
      for (int ntl = 0; ntl < 4; ntl++) {
        const short8 bfr = *(const short8*)(WihPk +
            (((size_t)kk * 32 + (4 * w + ntl)) * 64 + lane) * 8);
        #pragma unroll
        for (int mt = 0; mt < 4; mt++)
          acc[mt][ntl] = __builtin_amdgcn_mfma_f32_16x16x32_bf16(
              afr[mt], bfr, acc[mt][ntl], 0, 0, 0);
      }
    }
    __syncthreads();   // all reads of [cur] buffers complete

    // ---- epilogue: h_new = tanh(acc + bsum), write to [nxt] ----
    #pragma unroll
    for (int mt = 0; mt < 4; mt++) {
      #pragma unroll
      for (int ntl = 0; ntl < 4; ntl++) {
        int col = 64 * w + 16 * ntl + c;
        float bs = bsum[col];
        #pragma unroll
        for (int r = 0; r < 4; r++) {
          int row = mt * 16 + q * 4 + r;
          h_buf[nxt][row][col] = f2bf(tanh_fast(acc[mt][ntl][r] + bs));
        }
      }
    }
    {
      int row = tid >> 3, cb = (tid & 7) * 8;
      #pragma unroll
      for (int j = 0; j < 8; j++) u_buf[nxt][row][cb + j] = f2bf(upf[j]);
    }
    __syncthreads();   // writes to [nxt] visible

    // ---- head on output steps: out_t = h_t @ W_lin^T + b_lin ----
    if (s >= W_UP) {
      const int t = t0 + s - W_UP;
      const int mt = w & 3;
      const int ntb = (w >> 2) * 2;          // waves 0-3: nt {0,1}; 4-7: {2,3}
      f32x4 hacc[2];
      hacc[0] = (f32x4){0.f, 0.f, 0.f, 0.f};
      hacc[1] = (f32x4){0.f, 0.f, 0.f, 0.f};
      #pragma unroll 4
      for (int kk = 0; kk < 16; kk++) {
        short8 afr = *(const short8*)&h_buf[nxt][mt * 16 + c][kk * 32 + q * 8];
        #pragma unroll
        for (int i = 0; i < 2; i++) {
          const short8 bfr = *(const short8*)(WlinPk +
              (((size_t)kk * 4 + ntb + i) * 64 + lane) * 8);
          hacc[i] = __builtin_amdgcn_mfma_f32_16x16x32_bf16(afr, bfr, hacc[i], 0, 0, 0);
        }
      }
      #pragma unroll
      for (int i = 0; i < 2; i++) {
        int colo = (ntb + i) * 16 + c;
        float bl = blin_s[colo];
        #pragma unroll
        for (int r = 0; r < 4; r++) {
          int row = mt * 16 + q * 4 + r;
          out[((size_t)row * T_LEN + t) * N_OUT + colo] = hacc[i][r] + bl;
        }
      }
      // no extra barrier: next step writes the OTHER h buffer, and its
      // mid-step barrier orders those writes after this head's reads.
    }
  }
}

extern "C" void kernel_launch(void* const* d_in, const int* in_sizes, int n_in,
                              void* d_out, int out_size, void* d_ws, size_t ws_size,
                              hipStream_t stream) {
  const float* u     = (const float*)d_in[0];
  const float* W_ih  = (const float*)d_in[1];
  const float* W_hh  = (const float*)d_in[2];
  const float* b_ih  = (const float*)d_in[3];
  const float* b_hh  = (const float*)d_in[4];
  const float* omega = (const float*)d_in[5];
  const float* W_lin = (const float*)d_in[6];
  const float* b_lin = (const float*)d_in[7];
  float* out = (float*)d_out;

  unsigned short* Apk    = (unsigned short*)d_ws;                 // 512*512 bf16
  unsigned short* WihPk  = Apk + (size_t)H_DIM * H_DIM;           // 512*64
  unsigned short* WlinPk = WihPk + (size_t)H_DIM * N_IN;          // 512*64

  pack_kernel<<<160, 256, 0, stream>>>(W_ih, W_hh, omega, W_lin, Apk, WihPk, WlinPk);
  rnn_kernel<<<N_CH, 512, 0, stream>>>(u, b_ih, b_hh, b_lin, Apk, WihPk, WlinPk, out);
}

// Round 2
// 267.546 us; speedup vs baseline: 1.3924x; 1.3924x over previous
//
#include <hip/hip_runtime.h>

// rnn_lyapunov: B=64,T=2048,NIN=64,NH=512,NOUT=64
// Time-parallel chunked RNN: contraction ||A||<=~0.36 => W=12 warmup steps
// reconverge each chunk's state; chunk0's clamped-t warmup == the fixed-point
// iteration for h0. All GEMMs via mfma_f32_16x16x32_bf16.
// R1: L=16/W=12 + batch-split (redundancy 3x->1.75x), 1024 threads (4 waves/SIMD),
//     single barrier per step, fast tanh (v_rcp), biases in registers.

#define T_LEN 2048
#define B_SZ  64
#define H_DIM 512
#define N_IN  64
#define N_OUT 64
#define L_CH  16                 // output steps per chunk
#define W_UP  12                 // warmup steps per chunk
#define S_TOT (W_UP + L_CH)      // 28 steps per chunk
#define N_CH  (T_LEN / L_CH)     // 128 chunks x 2 batch-halves = 256 blocks
#define ST_H  568                // h_buf row stride (shorts): 16B-aligned rows, odd dword-quad stride
#define ST_U  88                 // u_buf row stride (shorts)

typedef __attribute__((ext_vector_type(8))) short short8;   // 8 bf16 in 4 VGPRs
typedef __attribute__((ext_vector_type(4))) float f32x4;

__device__ __forceinline__ unsigned short f2bf(float f) {
  union { float f; unsigned u; } v; v.f = f;
  return (unsigned short)((v.u + 0x7FFFu + ((v.u >> 16) & 1u)) >> 16);  // RNE
}

__device__ __forceinline__ float tanh_fast(float x) {
  // tanh(x) = 1 - 2/(exp(2x)+1); v_exp + v_rcp (bf16-accuracy is plenty)
  float e = __expf(2.f * x);
  float r = __builtin_amdgcn_rcpf(e + 1.f);
  return __builtin_fmaf(-2.f, r, 1.f);   // x->+inf: r=0 -> 1; x->-inf: r=1 -> -1
}

// ---- pack weights into MFMA B-operand fragment layout ----------------------
// B-frag for 16x16x32: lane L holds B[k = 32*kk + 8*(L>>4) + j][n = 16*nt + (L&15)]
// Apk  [kk=16][nt=32][lane=64][8] : B[k][n] = W_hh[n][k]*omega[k]^2
// WihPk[kk= 2][nt=32][lane=64][8] : B[k][n] = W_ih[n][k]      (k<64, n<512)
// WlinPk[kk=16][nt=4][lane=64][8] : B[k][n] = W_lin[n][k]     (k<512, n<64)
__global__ __launch_bounds__(256) void pack_kernel(
    const float* __restrict__ W_ih, const float* __restrict__ W_hh,
    const float* __restrict__ omega, const float* __restrict__ W_lin,
    unsigned short* __restrict__ Apk, unsigned short* __restrict__ WihPk,
    unsigned short* __restrict__ WlinPk)
{
  int id = blockIdx.x * 256 + threadIdx.x;
  if (id < 32768) {                       // A pack: (kk*32+nt)*64+lane
    int kk = id >> 11, rem = id & 2047, nt = rem >> 6, lane = rem & 63;
    int q = lane >> 4, c = lane & 15;
    int n = nt * 16 + c, kb = kk * 32 + q * 8;
    unsigned short* dst = Apk + (size_t)id * 8;
    #pragma unroll
    for (int j = 0; j < 8; j++) {
      int k = kb + j; float w = omega[k];
      dst[j] = f2bf(W_hh[(size_t)n * H_DIM + k] * w * w);
    }
  } else if (id < 36864) {                // W_ih pack
    int id2 = id - 32768;
    int kk = id2 >> 11, rem = id2 & 2047, nt = rem >> 6, lane = rem & 63;
    int q = lane >> 4, c = lane & 15;
    int n = nt * 16 + c, kb = kk * 32 + q * 8;
    unsigned short* dst = WihPk + (size_t)id2 * 8;
    #pragma unroll
    for (int j = 0; j < 8; j++) dst[j] = f2bf(W_ih[(size_t)n * N_IN + kb + j]);
  } else if (id < 40960) {                // W_lin pack
    int id3 = id - 36864;
    int kk = id3 >> 8, rem = id3 & 255, nt = rem >> 6, lane = rem & 63;
    int q = lane >> 4, c = lane & 15;
    int n = nt * 16 + c, kb = kk * 32 + q * 8;
    unsigned short* dst = WlinPk + (size_t)id3 * 8;
    #pragma unroll
    for (int j = 0; j < 8; j++) dst[j] = f2bf(W_lin[(size_t)n * H_DIM + kb + j]);
  }
}

#define MFMA(a, b, acc) __builtin_amdgcn_mfma_f32_16x16x32_bf16(a, b, acc, 0, 0, 0)

// ---- main time-parallel recurrence kernel ----------------------------------
// grid = 256 blocks = 128 chunks x 2 batch-halves (32 rows each); 1024 thr = 16 waves.
// Wave w owns h cols [32w, 32w+32) (nt tiles {2w, 2w+1}).
// One barrier per step: GEMM reads [cur] while epilogue writes [nxt] (disjoint).
__global__ __launch_bounds__(1024, 4) void rnn_kernel(
    const float* __restrict__ u, const float* __restrict__ b_ih,
    const float* __restrict__ b_hh, const float* __restrict__ b_lin,
    const unsigned short* __restrict__ Apk,
    const unsigned short* __restrict__ WihPk,
    const unsigned short* __restrict__ WlinPk,
    float* __restrict__ out)
{
  __shared__ __align__(16) unsigned short h_buf[2][32][ST_H];  // 72,704 B
  __shared__ __align__(16) unsigned short u_buf[2][32][ST_U];  // 11,264 B -> 83,968 B total (1 block/CU)

  const int tid = threadIdx.x;
  const int w = tid >> 6, lane = tid & 63, q = lane >> 4, c = lane & 15;
  const int chunk = blockIdx.x >> 1, bhalf = blockIdx.x & 1;
  const int row0 = bhalf * 32;
  const int t0 = chunk * L_CH;

  // biases hoisted to registers (constant across steps)
  const int col0 = 32 * w + c;
  const float bs0 = b_ih[col0] + b_hh[col0];
  const float bs1 = b_ih[col0 + 16] + b_hh[col0 + 16];
  const float blr = (w < 8) ? b_lin[((w >> 1) << 4) + c] : 0.f;

  for (int i = tid; i < 32 * ST_H; i += 1024)
    ((unsigned short*)h_buf[0])[i] = 0;                 // h starts at zero
  {    // stage u for step 0: t_in(0) = max(t0 - W, 0)
    int t = t0 - W_UP; if (t < 0) t = 0;
    int row = tid >> 5, cb = (tid & 31) * 2;
    const float* src = u + ((size_t)(row0 + row) * T_LEN + t) * N_IN + cb;
    u_buf[0][row][cb]     = f2bf(src[0]);
    u_buf[0][row][cb + 1] = f2bf(src[1]);
  }
  __syncthreads();

  f32x4 acc[2][2];

  for (int s = 0; s < S_TOT; s++) {
    const int cur = s & 1, nxt = cur ^ 1;

    // prefetch u for next step into registers
    float up0, up1;
    {
      int tn = t0 - W_UP + s + 1;
      tn = tn < 0 ? 0 : (tn > T_LEN - 1 ? T_LEN - 1 : tn);
      int row = tid >> 5, cb = (tid & 31) * 2;
      const float* src = u + ((size_t)(row0 + row) * T_LEN + tn) * N_IN + cb;
      up0 = src[0]; up1 = src[1];
    }

    acc[0][0] = acc[0][1] = acc[1][0] = acc[1][1] = (f32x4){0.f, 0.f, 0.f, 0.f};

    // ---- h @ A^T : K = 512 (A-frags from LDS, B-frags streamed from L2) ----
    {
      const unsigned short* apB = Apk + ((size_t)(2 * w) * 64 + lane) * 8;
      #pragma unroll 4
      for (int kk = 0; kk < 16; kk++) {
        const short8 a0 = *(const short8*)&h_buf[cur][c][kk * 32 + q * 8];
        const short8 a1 = *(const short8*)&h_buf[cur][16 + c][kk * 32 + q * 8];
        const unsigned short* bp = apB + (size_t)kk * (32 * 64 * 8);
        const short8 b0 = *(const short8*)bp;
        const short8 b1 = *(const short8*)(bp + 64 * 8);
        acc[0][0] = MFMA(a0, b0, acc[0][0]);
        acc[1][0] = MFMA(a1, b0, acc[1][0]);
        acc[0][1] = MFMA(a0, b1, acc[0][1]);
        acc[1][1] = MFMA(a1, b1, acc[1][1]);
      }
    }
    // ---- + u_t @ W_ih^T : K = 64, same accumulators ----
    {
      const unsigned short* wpB = WihPk + ((size_t)(2 * w) * 64 + lane) * 8;
      #pragma unroll
      for (int kk = 0; kk < 2; kk++) {
        const short8 a0 = *(const short8*)&u_buf[cur][c][kk * 32 + q * 8];
        const short8 a1 = *(const short8*)&u_buf[cur][16 + c][kk * 32 + q * 8];
        const unsigned short* bp = wpB + (size_t)kk * (32 * 64 * 8);
        const short8 b0 = *(const short8*)bp;
        const short8 b1 = *(const short8*)(bp + 64 * 8);
        acc[0][0] = MFMA(a0, b0, acc[0][0]);
        acc[1][0] = MFMA(a1, b0, acc[1][0]);
        acc[0][1] = MFMA(a0, b1, acc[0][1]);
        acc[1][1] = MFMA(a1, b1, acc[1][1]);
      }
    }

    // ---- epilogue: h_new = tanh(acc + bias) -> h_buf[nxt] (no barrier needed:
    // [cur] readers and [nxt] writers are disjoint buffers) ----
    #pragma unroll
    for (int mt = 0; mt < 2; mt++) {
      #pragma unroll
      for (int ntl = 0; ntl < 2; ntl++) {
        const float bs = ntl ? bs1 : bs0;
        const int col = 32 * w + 16 * ntl + c;
        #pragma unroll
        for (int r = 0; r < 4; r++)
          h_buf[nxt][mt * 16 + q * 4 + r][col] = f2bf(tanh_fast(acc[mt][ntl][r] + bs));
      }
    }
    {
      int row = tid >> 5, cb = (tid & 31) * 2;
      u_buf[nxt][row][cb]     = f2bf(up0);
      u_buf[nxt][row][cb + 1] = f2bf(up1);
    }
    __syncthreads();   // single barrier: [nxt] writes visible to head + next GEMM

    // ---- head on output steps: out_t = h_t @ W_lin^T + b_lin (waves 0-7) ----
    if (s >= W_UP && w < 8) {
      const int t = t0 + s - W_UP;
      const int mt = w & 1, nto = w >> 1;
      f32x4 hacc = (f32x4){0.f, 0.f, 0.f, 0.f};
      const unsigned short* lpB = WlinPk + ((size_t)nto * 64 + lane) * 8;
      #pragma unroll 4
      for (int kk = 0; kk < 16; kk++) {
        const short8 a = *(const short8*)&h_buf[nxt][mt * 16 + c][kk * 32 + q * 8];
        const short8 b = *(const short8*)(lpB + (size_t)kk * (4 * 64 * 8));
        hacc = MFMA(a, b, hacc);
      }
      #pragma unroll
      for (int r = 0; r < 4; r++)
        out[((size_t)(row0 + mt * 16 + q * 4 + r) * T_LEN + t) * N_OUT + nto * 16 + c]
            = hacc[r] + blr;
    }
  }
}

extern "C" void kernel_launch(void* const* d_in, const int* in_sizes, int n_in,
                              void* d_out, int out_size, void* d_ws, size_t ws_size,
                              hipStream_t stream) {
  const float* u     = (const float*)d_in[0];
  const float* W_ih  = (const float*)d_in[1];
  const float* W_hh  = (const float*)d_in[2];
  const float* b_ih  = (const float*)d_in[3];
  const float* b_hh  = (const float*)d_in[4];
  const float* omega = (const float*)d_in[5];
  const float* W_lin = (const float*)d_in[6];
  const float* b_lin = (const float*)d_in[7];
  float* out = (float*)d_out;

  unsigned short* Apk    = (unsigned short*)d_ws;                 // 512*512 bf16
  unsigned short* WihPk  = Apk + (size_t)H_DIM * H_DIM;           // 512*64
  unsigned short* WlinPk = WihPk + (size_t)H_DIM * N_IN;          // 512*64

  pack_kernel<<<160, 256, 0, stream>>>(W_ih, W_hh, omega, W_lin, Apk, WihPk, WlinPk);
  rnn_kernel<<<256, 1024, 0, stream>>>(u, b_ih, b_hh, b_lin, Apk, WihPk, WlinPk, out);
}

// Round 3
// 256.738 us; speedup vs baseline: 1.4510x; 1.0421x over previous
//
#include <hip/hip_runtime.h>

// rnn_lyapunov: B=64,T=2048,NIN=64,NH=512,NOUT=64
// Time-parallel chunked RNN: contraction ||A||<=0.36 => W=8 warmup steps
// reconverge each chunk; chunk0's clamped-t warmup == the h0 fixed-point iter.
// R3: M=64 (full batch/block) halves L2 A-stream per useful step -> compute-
// bound; operands flipped (weights=A-op, h=B-op) so D=[hidden][batch]: b64
// epilogue LDS writes + dwordx4 head stores; coalesced LDS-transpose pack.

#define T_LEN 2048
#define H_DIM 512
#define N_IN  64
#define N_OUT 64
#define L_CH  8                  // output steps per chunk
#define W_UP  8                  // warmup steps per chunk
#define S_TOT (W_UP + L_CH)      // 16 steps per chunk
#define ST_H  520                // h_buf row stride (shorts): 16B-aligned, bank-uniform
#define ST_U  72                 // u_buf row stride (shorts): 16B-aligned

typedef __attribute__((ext_vector_type(8))) short short8;   // 8 bf16 in 4 VGPRs
typedef __attribute__((ext_vector_type(4))) float f32x4;

__device__ __forceinline__ unsigned short f2bf(float f) {
  union { float f; unsigned u; } v; v.f = f;
  return (unsigned short)((v.u + 0x7FFFu + ((v.u >> 16) & 1u)) >> 16);  // RNE
}
__device__ __forceinline__ unsigned pack2bf(float a, float b) {
  return (unsigned)f2bf(a) | ((unsigned)f2bf(b) << 16);
}
__device__ __forceinline__ float tanh_fast(float x) {
  float e = __expf(2.f * x);
  float r = __builtin_amdgcn_rcpf(e + 1.f);
  return __builtin_fmaf(-2.f, r, 1.f);   // +inf: r=0 -> 1; -inf: r=1 -> -1
}

#define MFMA(a, b, acc) __builtin_amdgcn_mfma_f32_16x16x32_bf16(a, b, acc, 0, 0, 0)

// ---- pack weights into MFMA A-operand fragment layout ----------------------
// A-frag 16x16x32: lane L holds A[m = 16*mt + (L&15)][k = 32*kk + 8*(L>>4) + j]
// Apk  [kk=16][mt=32][lane][8] : W_hh[m][k]*omega[k]^2   (m,k < 512)
// WihPk[kk= 2][mt=32][lane][8] : W_ih[m][k]              (m<512, k<64)
// WlinPk[kk=16][mt=4][lane][8] : W_lin[m][k]             (m<64, k<512)
// Coalesced: phase1 stages a 32-wide k-slice (all rows) in LDS, phase2 writes
// the packed block as one contiguous span of b128s.
__global__ __launch_bounds__(256) void pack_kernel(
    const float* __restrict__ W_ih, const float* __restrict__ W_hh,
    const float* __restrict__ omega, const float* __restrict__ W_lin,
    unsigned short* __restrict__ Apk, unsigned short* __restrict__ WihPk,
    unsigned short* __restrict__ WlinPk)
{
  __shared__ unsigned short Lh[512][40];     // 40: even-8 stride, 16B-aligned rows
  const int tid = threadIdx.x, bid = blockIdx.x;
  const int l32 = tid & 31, nr = tid >> 5;

  if (bid < 16) {                            // ---- A: kk = bid
    const int k0 = bid * 32;
    const float om = omega[k0 + l32];
    const float om2 = om * om;
    for (int n = nr; n < 512; n += 8)
      Lh[n][l32] = f2bf(W_hh[(size_t)n * 512 + k0 + l32] * om2);
    __syncthreads();
    const int mt = tid >> 3, lane0 = (tid & 7) * 8;
    unsigned short* dst = Apk + (size_t)bid * 16384 + (size_t)tid * 64;
    #pragma unroll
    for (int l = 0; l < 8; l++) {
      const int lane = lane0 + l, c = lane & 15, q = lane >> 4;
      *(short8*)(dst + l * 8) = *(const short8*)&Lh[mt * 16 + c][q * 8];
    }
  } else if (bid < 18) {                     // ---- W_ih: kk = bid-16
    const int kk = bid - 16, k0 = kk * 32;
    for (int n = nr; n < 512; n += 8)
      Lh[n][l32] = f2bf(W_ih[(size_t)n * 64 + k0 + l32]);
    __syncthreads();
    const int mt = tid >> 3, lane0 = (tid & 7) * 8;
    unsigned short* dst = WihPk + (size_t)kk * 16384 + (size_t)tid * 64;
    #pragma unroll
    for (int l = 0; l < 8; l++) {
      const int lane = lane0 + l, c = lane & 15, q = lane >> 4;
      *(short8*)(dst + l * 8) = *(const short8*)&Lh[mt * 16 + c][q * 8];
    }
  } else {                                   // ---- W_lin: kk = bid-18
    const int kk = bid - 18, k0 = kk * 32;
    for (int n = nr; n < 64; n += 8)
      Lh[n][l32] = f2bf(W_lin[(size_t)n * 512 + k0 + l32]);
    __syncthreads();
    const int mt = tid >> 6, lane = tid & 63, c = lane & 15, q = lane >> 4;
    unsigned short* dst = WlinPk + (size_t)kk * 2048 + (size_t)tid * 8;
    *(short8*)dst = *(const short8*)&Lh[mt * 16 + c][q * 8];
  }
}

// ---- main time-parallel recurrence kernel ----------------------------------
// 256 blocks (1 chunk, full batch M=64), 1024 threads = 16 waves (1 block/CU).
// Wave w owns hidden m-tiles {2w, 2w+1}; all 4 batch n-tiles.
// One barrier per step: GEMM reads h_buf[cur], epilogue writes h_buf[nxt].
__global__ __launch_bounds__(1024, 4) void rnn_kernel(
    const float* __restrict__ u, const float* __restrict__ b_ih,
    const float* __restrict__ b_hh, const float* __restrict__ b_lin,
    const unsigned short* __restrict__ Apk,
    const unsigned short* __restrict__ WihPk,
    const unsigned short* __restrict__ WlinPk,
    float* __restrict__ out)
{
  __shared__ __align__(16) unsigned short h_buf[2][64][ST_H];  // 133,120 B
  __shared__ __align__(16) unsigned short u_buf[2][64][ST_U];  //  18,432 B

  const int tid = threadIdx.x;
  const int w = tid >> 6, lane = tid & 63, q = lane >> 4, c = lane & 15;
  const int t0 = blockIdx.x * L_CH;

  // biases in registers: lane's 4 D-rows are consecutive hidden/out indices
  f32x4 bsum[2];
  #pragma unroll
  for (int mt = 0; mt < 2; mt++) {
    const int n0 = (2 * w + mt) * 16 + q * 4;
    bsum[mt] = *(const f32x4*)(b_ih + n0) + *(const f32x4*)(b_hh + n0);
  }
  const int ot = w & 3, bth = w >> 2;        // head: out-tile, batch-tile
  const f32x4 blin4 = *(const f32x4*)(b_lin + ot * 16 + q * 4);

  for (int i = tid; i < 64 * ST_H / 2; i += 1024) ((unsigned*)h_buf[0])[i] = 0;
  {    // stage u for step 0: t_in(0) = max(t0 - W, 0)
    int t = t0 - W_UP; if (t < 0) t = 0;
    const int row = tid >> 4, cb = (tid & 15) * 4;
    const float* src = u + ((size_t)row * T_LEN + t) * N_IN + cb;
    unsigned* d = (unsigned*)&u_buf[0][row][cb];
    d[0] = pack2bf(src[0], src[1]); d[1] = pack2bf(src[2], src[3]);
  }
  __syncthreads();

  f32x4 acc[2][4];

  for (int s = 0; s < S_TOT; s++) {
    const int cur = s & 1, nxt = cur ^ 1;

    // prefetch next step's u into registers (coalesced dwordx4)
    float up0, up1, up2, up3;
    {
      int tn = t0 - W_UP + s + 1;
      tn = tn < 0 ? 0 : (tn > T_LEN - 1 ? T_LEN - 1 : tn);
      const int row = tid >> 4, cb = (tid & 15) * 4;
      const float* src = u + ((size_t)row * T_LEN + tn) * N_IN + cb;
      up0 = src[0]; up1 = src[1]; up2 = src[2]; up3 = src[3];
    }

    #pragma unroll
    for (int mt = 0; mt < 2; mt++)
      #pragma unroll
      for (int bt = 0; bt < 4; bt++)
        acc[mt][bt] = (f32x4){0.f, 0.f, 0.f, 0.f};

    // ---- A(weights, L2-stream) x h(LDS): K = 512 ----
    {
      const unsigned short* apA = Apk + ((size_t)(2 * w) * 64 + lane) * 8;
      #pragma unroll 4
      for (int kk = 0; kk < 16; kk++) {
        short8 hf[4];
        #pragma unroll
        for (int bt = 0; bt < 4; bt++)
          hf[bt] = *(const short8*)&h_buf[cur][bt * 16 + c][kk * 32 + q * 8];
        const short8 a0 = *(const short8*)(apA + (size_t)kk * 16384);
        const short8 a1 = *(const short8*)(apA + (size_t)kk * 16384 + 512);
        #pragma unroll
        for (int bt = 0; bt < 4; bt++) {
          acc[0][bt] = MFMA(a0, hf[bt], acc[0][bt]);
          acc[1][bt] = MFMA(a1, hf[bt], acc[1][bt]);
        }
      }
    }
    // ---- + W_ih x u_t: K = 64, same accumulators ----
    {
      const unsigned short* wpA = WihPk + ((size_t)(2 * w) * 64 + lane) * 8;
      #pragma unroll
      for (int kk = 0; kk < 2; kk++) {
        short8 uf[4];
        #pragma unroll
        for (int bt = 0; bt < 4; bt++)
          uf[bt] = *(const short8*)&u_buf[cur][bt * 16 + c][kk * 32 + q * 8];
        const short8 a0 = *(const short8*)(wpA + (size_t)kk * 16384);
        const short8 a1 = *(const short8*)(wpA + (size_t)kk * 16384 + 512);
        #pragma unroll
        for (int bt = 0; bt < 4; bt++) {
          acc[0][bt] = MFMA(a0, uf[bt], acc[0][bt]);
          acc[1][bt] = MFMA(a1, uf[bt], acc[1][bt]);
        }
      }
    }

    // ---- epilogue: h_new = tanh(acc + bias); lane writes 4 consecutive
    // hidden cols per (mt,bt) -> b64 LDS writes, conflict-free ----
    #pragma unroll
    for (int mt = 0; mt < 2; mt++) {
      #pragma unroll
      for (int bt = 0; bt < 4; bt++) {
        const unsigned lo = pack2bf(tanh_fast(acc[mt][bt][0] + bsum[mt][0]),
                                    tanh_fast(acc[mt][bt][1] + bsum[mt][1]));
        const unsigned hi = pack2bf(tanh_fast(acc[mt][bt][2] + bsum[mt][2]),
                                    tanh_fast(acc[mt][bt][3] + bsum[mt][3]));
        unsigned* d = (unsigned*)&h_buf[nxt][bt * 16 + c][(2 * w + mt) * 16 + q * 4];
        d[0] = lo; d[1] = hi;
      }
    }
    {
      const int row = tid >> 4, cb = (tid & 15) * 4;
      unsigned* d = (unsigned*)&u_buf[nxt][row][cb];
      d[0] = pack2bf(up0, up1); d[1] = pack2bf(up2, up3);
    }
    __syncthreads();   // single barrier: [nxt] visible to head + next GEMM

    // ---- head: out_t = W_lin x h_t + b_lin; lane stores 4 consecutive
    // out cols -> global dwordx4 ----
    if (s >= W_UP) {
      const int t = t0 + s - W_UP;
      f32x4 hacc = (f32x4){0.f, 0.f, 0.f, 0.f};
      const unsigned short* lpA = WlinPk + ((size_t)ot * 64 + lane) * 8;
      #pragma unroll 4
      for (int kk = 0; kk < 16; kk++) {
        const short8 hfr = *(const short8*)&h_buf[nxt][bth * 16 + c][kk * 32 + q * 8];
        const short8 a = *(const short8*)(lpA + (size_t)kk * 2048);
        hacc = MFMA(a, hfr, hacc);
      }
      const f32x4 res = hacc + blin4;
      float* op = out + ((size_t)(bth * 16 + c) * T_LEN + t) * N_OUT + ot * 16 + q * 4;
      *(f32x4*)op = res;
    }
  }
}

extern "C" void kernel_launch(void* const* d_in, const int* in_sizes, int n_in,
                              void* d_out, int out_size, void* d_ws, size_t ws_size,
                              hipStream_t stream) {
  const float* u     = (const float*)d_in[0];
  const float* W_ih  = (const float*)d_in[1];
  const float* W_hh  = (const float*)d_in[2];
  const float* b_ih  = (const float*)d_in[3];
  const float* b_hh  = (const float*)d_in[4];
  const float* omega = (const float*)d_in[5];
  const float* W_lin = (const float*)d_in[6];
  const float* b_lin = (const float*)d_in[7];
  float* out = (float*)d_out;

  unsigned short* Apk    = (unsigned short*)d_ws;                 // 512*512 bf16
  unsigned short* WihPk  = Apk + (size_t)H_DIM * H_DIM;           // 512*64
  unsigned short* WlinPk = WihPk + (size_t)H_DIM * N_IN;          // 64*512

  pack_kernel<<<34, 256, 0, stream>>>(W_ih, W_hh, omega, W_lin, Apk, WihPk, WlinPk);
  rnn_kernel<<<T_LEN / L_CH, 1024, 0, stream>>>(u, b_ih, b_hh, b_lin,
                                                Apk, WihPk, WlinPk, out);
}